// Round 9
// baseline (41.546 us; speedup 1.0000x reference)
//
#include <hip/hip_runtime.h>
#include <math.h>

#define BATCH 4
#define NPTS  8000
#define NCH   256
#define GDIM  20            // 20^3 = 8000 cells, ~1 point/cell
#define NCELL (GDIM*GDIM*GDIM)
#define CELLH (1.0f/GDIM)
#define EPS   1e-5f

// ws layout (bytes):
//   starts : [B][NCELL+16] int @ 0       (128256, rounded to 131072)
//   psort  : [B][NPTS] float4  @ 131072  (512000) (x,y,z,|p|^2), sorted by cell
//   sidx   : [B][NPTS] int     @ 643072  (128000) original index, same order
// total: 771072 bytes
#define STRIDE_ST (NCELL + 16)
#define WS_STARTS 0
#define WS_PSORT  131072
#define WS_SIDX   643072

__device__ __forceinline__ int cell_clamp(float v) {
  int c = (int)(v * (float)GDIM);
  return c < 0 ? 0 : (c > GDIM - 1 ? GDIM - 1 : c);
}

// One block per batch: LDS histogram -> shuffle-scan (3 barriers) -> global
// starts (+ sentinel) + scatter into psort/sidx via LDS cursors.
// Threads 0..999 own 8 cells each (1000*8 == NCELL).
__global__ __launch_bounds__(1024) void build_kernel(const float* __restrict__ points,
                                                     int* __restrict__ starts,
                                                     float4* __restrict__ psort,
                                                     int* __restrict__ sidx) {
  __shared__ int lst[NCELL];
  __shared__ int wtot[16];
  const int t = threadIdx.x;
  const int b = blockIdx.x;
  if (t < 1000) {
#pragma unroll
    for (int k = 0; k < 8; ++k) lst[t * 8 + k] = 0;
  }
  __syncthreads();

  const float* pb = points + (size_t)b * NPTS * 3;
  float px[8], py[8], pz[8];
  int pc[8];
#pragma unroll
  for (int k = 0; k < 8; ++k) {
    const int j = t + k * 1024;
    pc[k] = -1;
    if (j < NPTS) {
      px[k] = pb[j * 3 + 0];
      py[k] = pb[j * 3 + 1];
      pz[k] = pb[j * 3 + 2];
      pc[k] = (cell_clamp(pz[k]) * GDIM + cell_clamp(py[k])) * GDIM + cell_clamp(px[k]);
      atomicAdd(&lst[pc[k]], 1);
    }
  }
  __syncthreads();

  // per-thread sum of its 8 cells
  int v[8];
  int sum = 0;
  if (t < 1000) {
#pragma unroll
    for (int k = 0; k < 8; ++k) {
      v[k] = lst[t * 8 + k];
      sum += v[k];
    }
  }
  // wave-level inclusive scan of thread sums, then 16-wave total scan
  const int lane = t & 63, wv = t >> 6;
  int incl = sum;
#pragma unroll
  for (int d = 1; d < 64; d <<= 1) {
    const int u = __shfl_up(incl, d);
    if (lane >= d) incl += u;
  }
  if (lane == 63) wtot[wv] = incl;
  __syncthreads();
  if (wv == 0) {
    int x = (lane < 16) ? wtot[lane] : 0;
#pragma unroll
    for (int d = 1; d < 16; d <<= 1) {
      const int u = __shfl_up(x, d);
      if (lane >= d) x += u;
    }
    if (lane < 16) wtot[lane] = x;
  }
  __syncthreads();
  const int base = incl - sum + (wv ? wtot[wv - 1] : 0);

  int* stg = starts + b * STRIDE_ST;
  if (t < 1000) {
    int run = base;
#pragma unroll
    for (int k = 0; k < 8; ++k) {
      stg[t * 8 + k] = run;
      lst[t * 8 + k] = run;  // own cells only: no race
      run += v[k];
    }
  }
  if (t == 0) stg[NCELL] = NPTS;  // sentinel: end of last cell
  __syncthreads();

  // scatter (LDS cursors); psort.w carries |p|^2, sidx carries orig index
  float4* psb = psort + (size_t)b * NPTS;
  int* sib = sidx + (size_t)b * NPTS;
#pragma unroll
  for (int k = 0; k < 8; ++k) {
    if (pc[k] >= 0) {
      const int pos = atomicAdd(&lst[pc[k]], 1);
      const float sq = px[k] * px[k] + py[k] * py[k] + pz[k] * pz[k];
      psb[pos] = make_float4(px[k], py[k], pz[k], sq);
      sib[pos] = t + k * 1024;
    }
  }
}

// Top-1-OTHER accumulation: the K=2 set is always {self, nearest-other}
// (exact-duplicate ties still yield the same 2-set; output is the set mean).
// Key (max(d2,0), j) lexicographic == reference sort key + stable tie-break.
// p != i folded into the compare: no divergence, self skipped.
#define SCAN_RANGE(P0, P1)                                        \
  for (int p = (P0); p < (P1); ++p) {                             \
    const float4 P = ps[p];                                       \
    const int j = si[p];                                          \
    const float dot = xi * P.x + yi * P.y + zi * P.z;             \
    const float d2 = fmaxf((sqi + P.w) - 2.0f * dot, 0.0f);       \
    const bool lt = (p != i) &&                                   \
        ((d2 < b0) || (d2 == b0 && j < j0));                      \
    b0 = lt ? d2 : b0;                                            \
    j0 = lt ? j : j0;                                             \
  }

// Butterfly-merge of per-lane top-1 states (operates on mb0/mj0).
#define MERGE_XOR(MASK)                                           \
  {                                                               \
    const float ob = __shfl_xor(mb0, MASK);                       \
    const int oj = __shfl_xor(mj0, MASK);                         \
    const bool keep = (mb0 < ob) || (mb0 == ob && mj0 < oj);      \
    mb0 = keep ? mb0 : ob;                                        \
    mj0 = keep ? mj0 : oj;                                        \
  }

// Fused NN search + gather/mean. 256 threads = 16 sorted-order queries x
// 16 candidate-split lanes (500 blocks/batch). starts[] read from L2
// (32KB/batch, hot). Full r<=2 box (25 rows x 5 cells, ~125 pts) as
// row-ranges; conservative (2h)^2 stop bound on the merged other-best
// keeps the shell fallback ~1e-3 rare. Epilogue: 4 waves x 4 queries.
__global__ __launch_bounds__(256, 8) void search_gather_kernel(
    const float4* __restrict__ psort, const int* __restrict__ sidx,
    const int* __restrict__ starts, const float* __restrict__ preds,
    float* __restrict__ out) {
  __shared__ int snbr[16][2];  // j_other, qorig
  const int t = threadIdx.x;
  const int b = blockIdx.y;
  const int* stg = starts + b * STRIDE_ST;

  const int ql = t >> 4;  // 0..15
  const int s = t & 15;   // candidate split lane
  const int i = blockIdx.x * 16 + ql;  // 500*16 == 8000 exact
  const float4* ps = psort + (size_t)b * NPTS;
  const int* si = sidx + (size_t)b * NPTS;
  const float4 Q = ps[i];
  const float xi = Q.x, yi = Q.y, zi = Q.z;
  const float sqi = Q.w;
  const int qorig = si[i];
  const int cx = cell_clamp(xi), cy = cell_clamp(yi), cz = cell_clamp(zi);
  const int x0c = cx > 1 ? cx - 2 : 0;
  const int x1c = cx < GDIM - 2 ? cx + 2 : GDIM - 1;

  float b0 = INFINITY;
  int j0 = -1;

  // ---- r<=2 box: 25 rows, lane s takes rows s and s+16 ----
  int rs[2], re[2];
#pragma unroll
  for (int rr = 0; rr < 2; ++rr) {
    const int kk = s + rr * 16;
    int lo = 0, hi = 0;
    if (kk < 25) {
      const int z = cz + kk / 5 - 2;
      const int y = cy + kk % 5 - 2;
      if ((unsigned)z < GDIM && (unsigned)y < GDIM) {
        const int rowbase = (z * GDIM + y) * GDIM;
        lo = stg[rowbase + x0c];
        hi = stg[rowbase + x1c + 1];  // sentinel covers rowbase+x1c+1 == NCELL
      }
    }
    rs[rr] = lo;
    re[rr] = hi;
  }
#pragma unroll
  for (int rr = 0; rr < 2; ++rr) { SCAN_RANGE(rs[rr], re[rr]) }

  // merged copy (per-lane b0/j0 stay disjoint-set accumulators)
  float mb0 = b0;
  int mj0 = j0;
  MERGE_XOR(1) MERGE_XOR(2) MERGE_XOR(4) MERGE_XOR(8)

  if (!(mb0 + EPS <= (2.0f * CELLH) * (2.0f * CELLH))) {
    // ---- rare fallback: expanding Chebyshev shells r>=3, row-range form ----
    for (int r = 3; r <= GDIM; ++r) {
      const int W = 2 * r + 1;
      for (int idx = s; idx < W * W; idx += 16) {
        const int dz = idx / W - r;
        const int dy = idx % W - r;
        const int z = cz + dz, y = cy + dy;
        if ((unsigned)z >= GDIM || (unsigned)y >= GDIM) continue;
        const int rowbase = (z * GDIM + y) * GDIM;
        if (dz == -r || dz == r || dy == -r || dy == r) {
          const int xl = cx > r ? cx - r : 0;
          const int xh = cx < GDIM - 1 - r ? cx + r : GDIM - 1;
          const int lo = stg[rowbase + xl], hi = stg[rowbase + xh + 1];
          SCAN_RANGE(lo, hi)
        } else {
          if (cx - r >= 0) {
            const int lo = stg[rowbase + cx - r], hi = stg[rowbase + cx - r + 1];
            SCAN_RANGE(lo, hi)
          }
          if (cx + r <= GDIM - 1) {
            const int lo = stg[rowbase + cx + r], hi = stg[rowbase + cx + r + 1];
            SCAN_RANGE(lo, hi)
          }
        }
      }
      mb0 = b0; mj0 = j0;
      MERGE_XOR(1) MERGE_XOR(2) MERGE_XOR(4) MERGE_XOR(8)
      const float rb = (float)r * CELLH;
      if (mb0 + EPS <= rb * rb) break;
    }
  }

  if (s == 0) {
    snbr[ql][0] = mj0;
    snbr[ql][1] = qorig;
  }
  __syncthreads();

  // ---- gather + mean epilogue: wave w handles queries 4w..4w+3 ----
  const int wave = t >> 6;
  const int lane = t & 63;
  const float* predb = preds + (size_t)b * NPTS * NCH;
  float* outb = out + (size_t)b * NPTS * NCH;
#pragma unroll
  for (int k = 0; k < 4; ++k) {
    const int q = wave * 4 + k;
    const int c = snbr[q][0];
    const int qo = snbr[q][1];
    const float4 va = ((const float4*)(predb + (size_t)qo * NCH))[lane];
    const float4 vc = ((const float4*)(predb + (size_t)c * NCH))[lane];
    float4 r;
    r.x = 0.5f * (va.x + vc.x);
    r.y = 0.5f * (va.y + vc.y);
    r.z = 0.5f * (va.z + vc.z);
    r.w = 0.5f * (va.w + vc.w);
    ((float4*)(outb + (size_t)qo * NCH))[lane] = r;
  }
}

extern "C" void kernel_launch(void* const* d_in, const int* in_sizes, int n_in,
                              void* d_out, int out_size, void* d_ws, size_t ws_size,
                              hipStream_t stream) {
  const float* points = (const float*)d_in[0];
  const float* preds = (const float*)d_in[1];
  // d_in[2] (k_vector) unused: reference hardcodes k = 2.
  float* out = (float*)d_out;

  char* ws = (char*)d_ws;
  int* starts = (int*)(ws + WS_STARTS);
  float4* psort = (float4*)(ws + WS_PSORT);
  int* sidx = (int*)(ws + WS_SIDX);

  build_kernel<<<BATCH, 1024, 0, stream>>>(points, starts, psort, sidx);
  search_gather_kernel<<<dim3(NPTS / 16, BATCH), 256, 0, stream>>>(psort, sidx, starts, preds, out);
}

// Round 10
// 35.576 us; speedup vs baseline: 1.1678x; 1.1678x over previous
//
#include <hip/hip_runtime.h>
#include <math.h>

#define BATCH 4
#define NPTS  8000
#define NCH   256
#define GDIM  20            // 20^3 = 8000 cells, ~1 point/cell
#define NCELL (GDIM*GDIM*GDIM)
#define CELLH (1.0f/GDIM)
#define EPS   1e-5f

// ws layout (bytes):
//   starts : [B][NCELL+16] int @ 0       (128256, rounded to 131072)
//   psort  : [B][NPTS] float4  @ 131072  (512000) (x,y,z, bitcast(orig j))
// total: 643072 bytes
#define STRIDE_ST (NCELL + 16)
#define WS_STARTS 0
#define WS_PSORT  131072

__device__ __forceinline__ int cell_clamp(float v) {
  int c = (int)(v * (float)GDIM);
  return c < 0 ? 0 : (c > GDIM - 1 ? GDIM - 1 : c);
}

// One block per batch: LDS histogram -> shuffle-scan (3 barriers) -> global
// starts (+ sentinel) + scatter into psort via LDS cursors.
// Threads 0..999 own 8 cells each (1000*8 == NCELL).
__global__ __launch_bounds__(1024) void build_kernel(const float* __restrict__ points,
                                                     int* __restrict__ starts,
                                                     float4* __restrict__ psort) {
  __shared__ int lst[NCELL];
  __shared__ int wtot[16];
  const int t = threadIdx.x;
  const int b = blockIdx.x;
  if (t < 1000) {
#pragma unroll
    for (int k = 0; k < 8; ++k) lst[t * 8 + k] = 0;
  }
  __syncthreads();

  const float* pb = points + (size_t)b * NPTS * 3;
  float px[8], py[8], pz[8];
  int pc[8];
#pragma unroll
  for (int k = 0; k < 8; ++k) {
    const int j = t + k * 1024;
    pc[k] = -1;
    if (j < NPTS) {
      px[k] = pb[j * 3 + 0];
      py[k] = pb[j * 3 + 1];
      pz[k] = pb[j * 3 + 2];
      pc[k] = (cell_clamp(pz[k]) * GDIM + cell_clamp(py[k])) * GDIM + cell_clamp(px[k]);
      atomicAdd(&lst[pc[k]], 1);
    }
  }
  __syncthreads();

  // per-thread sum of its 8 cells
  int v[8];
  int sum = 0;
  if (t < 1000) {
#pragma unroll
    for (int k = 0; k < 8; ++k) {
      v[k] = lst[t * 8 + k];
      sum += v[k];
    }
  }
  // wave-level inclusive scan of thread sums, then 16-wave total scan
  const int lane = t & 63, wv = t >> 6;
  int incl = sum;
#pragma unroll
  for (int d = 1; d < 64; d <<= 1) {
    const int u = __shfl_up(incl, d);
    if (lane >= d) incl += u;
  }
  if (lane == 63) wtot[wv] = incl;
  __syncthreads();
  if (wv == 0) {
    int x = (lane < 16) ? wtot[lane] : 0;
#pragma unroll
    for (int d = 1; d < 16; d <<= 1) {
      const int u = __shfl_up(x, d);
      if (lane >= d) x += u;
    }
    if (lane < 16) wtot[lane] = x;
  }
  __syncthreads();
  const int base = incl - sum + (wv ? wtot[wv - 1] : 0);

  int* stg = starts + b * STRIDE_ST;
  if (t < 1000) {
    int run = base;
#pragma unroll
    for (int k = 0; k < 8; ++k) {
      stg[t * 8 + k] = run;
      lst[t * 8 + k] = run;  // own cells only: no race
      run += v[k];
    }
  }
  if (t == 0) stg[NCELL] = NPTS;  // sentinel: end of last cell
  __syncthreads();

  // scatter (LDS cursors); psort.w carries bitcast original index
  float4* psb = psort + (size_t)b * NPTS;
#pragma unroll
  for (int k = 0; k < 8; ++k) {
    if (pc[k] >= 0) {
      const int pos = atomicAdd(&lst[pc[k]], 1);
      psb[pos] = make_float4(px[k], py[k], pz[k], __int_as_float(t + k * 1024));
    }
  }
}

// Top-1-OTHER accumulation: the K=2 set is always {self, nearest-other}
// (exact-duplicate ties still yield the same 2-set; output is the set mean).
// Key (max(d2,0), j) lexicographic == reference sort key + stable tie-break.
// Self skipped via p != i folded into the compare (no divergence).
// ONE 16B load per candidate (R9 lesson: a second sidx[] load regressed 14%).
#define SCAN_RANGE(P0, P1)                                        \
  for (int p = (P0); p < (P1); ++p) {                             \
    const float4 P = ps[p];                                       \
    const float dot = xi * P.x + yi * P.y + zi * P.z;             \
    const float sqj = P.x * P.x + P.y * P.y + P.z * P.z;          \
    const float d2 = fmaxf((sqi + sqj) - 2.0f * dot, 0.0f);       \
    const int j = __float_as_int(P.w);                            \
    const bool lt = (p != i) &&                                   \
        ((d2 < b0) || (d2 == b0 && j < j0));                      \
    b0 = lt ? d2 : b0;                                            \
    j0 = lt ? j : j0;                                             \
  }

// Butterfly-merge of per-lane top-1 states (operates on mb0/mj0).
#define MERGE_XOR(MASK)                                           \
  {                                                               \
    const float ob = __shfl_xor(mb0, MASK);                       \
    const int oj = __shfl_xor(mj0, MASK);                         \
    const bool keep = (mb0 < ob) || (mb0 == ob && mj0 < oj);      \
    mb0 = keep ? mb0 : ob;                                        \
    mj0 = keep ? mj0 : oj;                                        \
  }

// Fused NN search + gather/mean. 256 threads = 16 sorted-order queries x
// 16 candidate-split lanes (500 blocks/batch). starts[] read from L2
// (32KB/batch, hot). Full r<=2 box (25 rows x 5 cells, ~125 pts) as
// row-ranges; conservative (2h)^2 stop bound on the merged other-best
// keeps the shell fallback ~1e-3 rare. Epilogue: 4 waves x 4 queries.
__global__ __launch_bounds__(256, 8) void search_gather_kernel(
    const float4* __restrict__ psort, const int* __restrict__ starts,
    const float* __restrict__ preds, float* __restrict__ out) {
  __shared__ int snbr[16][2];  // j_other, qorig
  const int t = threadIdx.x;
  const int b = blockIdx.y;
  const int* stg = starts + b * STRIDE_ST;

  const int ql = t >> 4;  // 0..15
  const int s = t & 15;   // candidate split lane
  const int i = blockIdx.x * 16 + ql;  // 500*16 == 8000 exact
  const float4* ps = psort + (size_t)b * NPTS;
  const float4 Q = ps[i];
  const float xi = Q.x, yi = Q.y, zi = Q.z;
  const int qorig = __float_as_int(Q.w);
  const float sqi = xi * xi + yi * yi + zi * zi;  // same expr as reference
  const int cx = cell_clamp(xi), cy = cell_clamp(yi), cz = cell_clamp(zi);
  const int x0c = cx > 1 ? cx - 2 : 0;
  const int x1c = cx < GDIM - 2 ? cx + 2 : GDIM - 1;

  float b0 = INFINITY;
  int j0 = -1;

  // ---- r<=2 box: 25 rows, lane s takes rows s and s+16 ----
  int rs[2], re[2];
#pragma unroll
  for (int rr = 0; rr < 2; ++rr) {
    const int kk = s + rr * 16;
    int lo = 0, hi = 0;
    if (kk < 25) {
      const int z = cz + kk / 5 - 2;
      const int y = cy + kk % 5 - 2;
      if ((unsigned)z < GDIM && (unsigned)y < GDIM) {
        const int rowbase = (z * GDIM + y) * GDIM;
        lo = stg[rowbase + x0c];
        hi = stg[rowbase + x1c + 1];  // sentinel covers rowbase+x1c+1 == NCELL
      }
    }
    rs[rr] = lo;
    re[rr] = hi;
  }
#pragma unroll
  for (int rr = 0; rr < 2; ++rr) { SCAN_RANGE(rs[rr], re[rr]) }

  // merged copy (per-lane b0/j0 stay disjoint-set accumulators)
  float mb0 = b0;
  int mj0 = j0;
  MERGE_XOR(1) MERGE_XOR(2) MERGE_XOR(4) MERGE_XOR(8)

  if (!(mb0 + EPS <= (2.0f * CELLH) * (2.0f * CELLH))) {
    // ---- rare fallback: expanding Chebyshev shells r>=3, row-range form ----
    for (int r = 3; r <= GDIM; ++r) {
      const int W = 2 * r + 1;
      for (int idx = s; idx < W * W; idx += 16) {
        const int dz = idx / W - r;
        const int dy = idx % W - r;
        const int z = cz + dz, y = cy + dy;
        if ((unsigned)z >= GDIM || (unsigned)y >= GDIM) continue;
        const int rowbase = (z * GDIM + y) * GDIM;
        if (dz == -r || dz == r || dy == -r || dy == r) {
          const int xl = cx > r ? cx - r : 0;
          const int xh = cx < GDIM - 1 - r ? cx + r : GDIM - 1;
          const int lo = stg[rowbase + xl], hi = stg[rowbase + xh + 1];
          SCAN_RANGE(lo, hi)
        } else {
          if (cx - r >= 0) {
            const int lo = stg[rowbase + cx - r], hi = stg[rowbase + cx - r + 1];
            SCAN_RANGE(lo, hi)
          }
          if (cx + r <= GDIM - 1) {
            const int lo = stg[rowbase + cx + r], hi = stg[rowbase + cx + r + 1];
            SCAN_RANGE(lo, hi)
          }
        }
      }
      mb0 = b0; mj0 = j0;
      MERGE_XOR(1) MERGE_XOR(2) MERGE_XOR(4) MERGE_XOR(8)
      const float rb = (float)r * CELLH;
      if (mb0 + EPS <= rb * rb) break;
    }
  }

  if (s == 0) {
    snbr[ql][0] = mj0;
    snbr[ql][1] = qorig;
  }
  __syncthreads();

  // ---- gather + mean epilogue: wave w handles queries 4w..4w+3 ----
  const int wave = t >> 6;
  const int lane = t & 63;
  const float* predb = preds + (size_t)b * NPTS * NCH;
  float* outb = out + (size_t)b * NPTS * NCH;
#pragma unroll
  for (int k = 0; k < 4; ++k) {
    const int q = wave * 4 + k;
    const int c = snbr[q][0];
    const int qo = snbr[q][1];
    const float4 va = ((const float4*)(predb + (size_t)qo * NCH))[lane];
    const float4 vc = ((const float4*)(predb + (size_t)c * NCH))[lane];
    float4 r;
    r.x = 0.5f * (va.x + vc.x);
    r.y = 0.5f * (va.y + vc.y);
    r.z = 0.5f * (va.z + vc.z);
    r.w = 0.5f * (va.w + vc.w);
    ((float4*)(outb + (size_t)qo * NCH))[lane] = r;
  }
}

extern "C" void kernel_launch(void* const* d_in, const int* in_sizes, int n_in,
                              void* d_out, int out_size, void* d_ws, size_t ws_size,
                              hipStream_t stream) {
  const float* points = (const float*)d_in[0];
  const float* preds = (const float*)d_in[1];
  // d_in[2] (k_vector) unused: reference hardcodes k = 2.
  float* out = (float*)d_out;

  char* ws = (char*)d_ws;
  int* starts = (int*)(ws + WS_STARTS);
  float4* psort = (float4*)(ws + WS_PSORT);

  build_kernel<<<BATCH, 1024, 0, stream>>>(points, starts, psort);
  search_gather_kernel<<<dim3(NPTS / 16, BATCH), 256, 0, stream>>>(psort, starts, preds, out);
}